// Round 1
// baseline (384.273 us; speedup 1.0000x reference)
//
#include <hip/hip_runtime.h>

// LSTM: B=2048, T=512, INPUT=2, H=32, OUT=1. One wave per batch element.
// Lane j (0..63) owns gate rows j and j+64 of the 4H=128 gates:
//   lanes 0..31  -> i_j (row j),    g_j (row j+64)
//   lanes 32..63 -> f_{j-32} (row), o_{j-32} (row)
// h[0..31] is wave-uniform -> broadcast via v_readlane into SGPRs, inner
// recurrent dot is v_fma with SGPR multiplier (no LDS, no shuffles).

#define BB 2048
#define TT 512
#define HH 32

__device__ __forceinline__ float sigm(float x) {
    // 1/(1+exp(-x)) with HW exp + HW rcp (avoids non-fast-math fdiv expansion)
    return __builtin_amdgcn_rcpf(1.0f + __expf(-x));
}

__global__ __launch_bounds__(256, 2) void lstm_fused_kernel(
    const float* __restrict__ x,     // [B, T, 2]
    const float* __restrict__ W_ih,  // [128, 2]
    const float* __restrict__ W_hh,  // [128, 32]
    const float* __restrict__ b_ih,  // [128]
    const float* __restrict__ b_hh,  // [128]
    const float* __restrict__ W_fc,  // [1, 32]
    const float* __restrict__ b_fc,  // [1]
    float* __restrict__ out)         // [B, T, 1]
{
    __shared__ float lds_x[4 * TT * 2];  // 16 KB: 4 waves/block, x per element

    const int lane = threadIdx.x & 63;
    const int wv   = threadIdx.x >> 6;
    const int b    = blockIdx.x * 4 + wv;

    // ---- stage this element's x[T,2] (4 KB) into LDS, coalesced float4 ----
    {
        const float4* xg = (const float4*)(x + (size_t)b * TT * 2);
        float4* xs = (float4*)(lds_x + wv * TT * 2);
        #pragma unroll
        for (int r = 0; r < 4; ++r) {
            xs[r * 64 + lane] = xg[r * 64 + lane];
        }
    }

    // ---- per-lane weights into registers ----
    const int rlo = lane;        // gate row (i or f)
    const int rhi = lane + 64;   // gate row (g or o)

    const float wihl0 = W_ih[rlo * 2 + 0], wihl1 = W_ih[rlo * 2 + 1];
    const float wihh0 = W_ih[rhi * 2 + 0], wihh1 = W_ih[rhi * 2 + 1];
    const float bl = b_ih[rlo] + b_hh[rlo];
    const float bh = b_ih[rhi] + b_hh[rhi];

    float wlo[HH], whi[HH];
    #pragma unroll
    for (int k = 0; k < 8; ++k) {
        float4 a = ((const float4*)(W_hh + rlo * HH))[k];
        wlo[4*k+0] = a.x; wlo[4*k+1] = a.y; wlo[4*k+2] = a.z; wlo[4*k+3] = a.w;
        float4 c4 = ((const float4*)(W_hh + rhi * HH))[k];
        whi[4*k+0] = c4.x; whi[4*k+1] = c4.y; whi[4*k+2] = c4.z; whi[4*k+3] = c4.w;
    }
    const float wfc = W_fc[lane & 31];
    const float bfc = b_fc[0];

    // activation selectors: lower half hi-gate is tanh (=2*sigm(2x)-1),
    // upper half hi-gate is sigmoid (=1*sigm(1x)+0). Branch-free.
    const float Mm = (lane < 32) ? 2.0f : 1.0f;
    const float Aa = (lane < 32) ? 2.0f : 1.0f;
    const float Bb = (lane < 32) ? -1.0f : 0.0f;

    // wave-uniform h in (hopefully) SGPRs
    float hs[HH];
    #pragma unroll
    for (int k = 0; k < HH; ++k) hs[k] = 0.0f;
    float c = 0.0f;

    float* out_b = out + (size_t)b * TT;
    const float2* xw = (const float2*)(lds_x + wv * TT * 2);

    __syncthreads();  // x staging visible (strictly intra-wave, but cheap & safe)

    #pragma unroll 1
    for (int t = 0; t < TT; ++t) {
        float2 xt = xw[t];  // wave-uniform ds_read_b64

        // gate pre-activations: bias + x-projection
        float glo = fmaf(xt.x, wihl0, fmaf(xt.y, wihl1, bl));
        float ghi = fmaf(xt.x, wihh0, fmaf(xt.y, wihh1, bh));

        // recurrent dot: h (SGPR) x W_hh rows (VGPR), 64 FMAs
        #pragma unroll
        for (int k = 0; k < HH; ++k) {
            glo = fmaf(hs[k], wlo[k], glo);
            ghi = fmaf(hs[k], whi[k], ghi);
        }

        float alo = sigm(glo);                       // i (lanes<32) / f (>=32)
        float ahi = fmaf(Aa, sigm(Mm * ghi), Bb);    // tanh g / sigmoid o

        float fsw = __shfl_xor(alo, 32);             // lane j<32 gets f_j
        float osw = __shfl_xor(ahi, 32);             // lane j<32 gets o_j

        c = fmaf(fsw, c, alo * ahi);                 // c = f*c + i*g  (lanes<32 valid)
        float tc = fmaf(2.0f, sigm(2.0f * c), -1.0f);  // tanh(c)
        float hnew = osw * tc;                       // h_j on lanes<32

        // broadcast new h to wave-uniform registers (v_readlane)
        #pragma unroll
        for (int k = 0; k < HH; ++k) {
            hs[k] = __uint_as_float(
                __builtin_amdgcn_readlane(__float_as_uint(hnew), k));
        }

        // FC head: out = sum_j h_j * wfc_j + bfc  (butterfly over lanes 0..31)
        float vr = hnew * wfc;
        vr += __shfl_xor(vr, 16);
        vr += __shfl_xor(vr, 8);
        vr += __shfl_xor(vr, 4);
        vr += __shfl_xor(vr, 2);
        vr += __shfl_xor(vr, 1);
        if (lane == 0) out_b[t] = vr + bfc;
    }
}

extern "C" void kernel_launch(void* const* d_in, const int* in_sizes, int n_in,
                              void* d_out, int out_size, void* d_ws, size_t ws_size,
                              hipStream_t stream) {
    const float* x    = (const float*)d_in[0];
    const float* W_ih = (const float*)d_in[1];
    const float* W_hh = (const float*)d_in[2];
    const float* b_ih = (const float*)d_in[3];
    const float* b_hh = (const float*)d_in[4];
    const float* W_fc = (const float*)d_in[5];
    const float* b_fc = (const float*)d_in[6];
    float* out = (float*)d_out;

    dim3 grid(BB / 4);   // 512 blocks, 4 waves (4 batch elements) each
    dim3 block(256);
    lstm_fused_kernel<<<grid, block, 0, stream>>>(x, W_ih, W_hh, b_ih, b_hh,
                                                  W_fc, b_fc, out);
}

// Round 2
// 293.856 us; speedup vs baseline: 1.3077x; 1.3077x over previous
//
#include <hip/hip_runtime.h>

// LSTM: B=2048, T=512, INPUT=2, H=32, OUT=1. One wave per batch element.
// Lane j (0..63) owns gate rows j and j+64 of the 4H=128 gates:
//   lanes 0..31  -> i_j (row j),    g_j (row j+64)
//   lanes 32..63 -> f_{j-32} (row), o_{j-32} (row)
// h[0..31] is wave-uniform -> v_readlane into SGPRs; recurrent dot is
// v_fma with SGPR multiplier. FC head deferred: h written to LDS per step,
// reduced in 64-step chunks with a coalesced store (kills the per-step
// serial shuffle butterfly from round 1).

#define BB 2048
#define TT 512
#define HH 32
#define CHUNK 64
#define HROW 33   // LDS row stride in floats: conflict-free ((lane+u)%32)

__device__ __forceinline__ float sigm(float x) {
    return __builtin_amdgcn_rcpf(1.0f + __expf(-x));
}

__global__ __launch_bounds__(256, 2) void lstm_fused_kernel(
    const float* __restrict__ x,     // [B, T, 2]
    const float* __restrict__ W_ih,  // [128, 2]
    const float* __restrict__ W_hh,  // [128, 32]
    const float* __restrict__ b_ih,  // [128]
    const float* __restrict__ b_hh,  // [128]
    const float* __restrict__ W_fc,  // [1, 32]
    const float* __restrict__ b_fc,  // [1]
    float* __restrict__ out)         // [B, T, 1]
{
    __shared__ float lds_x[4 * TT * 2];            // 16 KB
    __shared__ float lds_h[4 * CHUNK * HROW];      // 33 KB: per-wave h history

    const int lane = threadIdx.x & 63;
    const int wv   = threadIdx.x >> 6;
    const int b    = blockIdx.x * 4 + wv;

    // ---- stage x[T,2] (4 KB/elem) into LDS, coalesced float4 ----
    {
        const float4* xg = (const float4*)(x + (size_t)b * TT * 2);
        float4* xs = (float4*)(lds_x + wv * TT * 2);
        #pragma unroll
        for (int r = 0; r < 4; ++r) xs[r * 64 + lane] = xg[r * 64 + lane];
    }

    // ---- per-lane weights ----
    const int rlo = lane;
    const int rhi = lane + 64;
    const float wihl0 = W_ih[rlo * 2 + 0], wihl1 = W_ih[rlo * 2 + 1];
    const float wihh0 = W_ih[rhi * 2 + 0], wihh1 = W_ih[rhi * 2 + 1];
    const float bl = b_ih[rlo] + b_hh[rlo];
    const float bh = b_ih[rhi] + b_hh[rhi];

    float wlo[HH], whi[HH];
    #pragma unroll
    for (int k = 0; k < 8; ++k) {
        float4 a = ((const float4*)(W_hh + rlo * HH))[k];
        wlo[4*k+0] = a.x; wlo[4*k+1] = a.y; wlo[4*k+2] = a.z; wlo[4*k+3] = a.w;
        float4 c4 = ((const float4*)(W_hh + rhi * HH))[k];
        whi[4*k+0] = c4.x; whi[4*k+1] = c4.y; whi[4*k+2] = c4.z; whi[4*k+3] = c4.w;
    }
    const float bfc = b_fc[0];

    // activation selectors (branch-free): lanes<32 hi-gate = tanh
    const float Mm = (lane < 32) ? 2.0f : 1.0f;
    const float Aa = (lane < 32) ? 2.0f : 1.0f;
    const float Bb = (lane < 32) ? -1.0f : 0.0f;

    float hs[HH];
    #pragma unroll
    for (int k = 0; k < HH; ++k) hs[k] = 0.0f;
    float c = 0.0f;

    float* out_b = out + (size_t)b * TT;
    const float2* xw = (const float2*)(lds_x + wv * TT * 2);
    float* hb = lds_h + wv * CHUNK * HROW;

    __syncthreads();

    #pragma unroll 1
    for (int t = 0; t < TT; ++t) {
        float2 xt = xw[t];

        float g0 = fmaf(xt.x, wihl0, fmaf(xt.y, wihl1, bl));
        float g1 = 0.0f;
        float h0 = fmaf(xt.x, wihh0, fmaf(xt.y, wihh1, bh));
        float h1 = 0.0f;

        // recurrent dot, 2 chains per gate (16-FMA dependency depth)
        #pragma unroll
        for (int k = 0; k < HH / 2; ++k) {
            g0 = fmaf(hs[k],          wlo[k],          g0);
            g1 = fmaf(hs[k + HH/2],   wlo[k + HH/2],   g1);
            h0 = fmaf(hs[k],          whi[k],          h0);
            h1 = fmaf(hs[k + HH/2],   whi[k + HH/2],   h1);
        }
        float glo = g0 + g1;
        float ghi = h0 + h1;

        float alo = sigm(glo);                      // i (lanes<32) / f
        float ahi = fmaf(Aa, sigm(Mm * ghi), Bb);   // tanh g / sigmoid o

        float fsw = __shfl_xor(alo, 32);            // lanes<32: f_j
        float osw = __shfl_xor(ahi, 32);            // lanes<32: o_j

        c = fmaf(fsw, c, alo * ahi);                // c = f*c + i*g (lanes<32)
        float tc = fmaf(2.0f, sigm(2.0f * c), -1.0f);
        float hnew = osw * tc;                      // h_j on lanes<32

        // stash h for deferred FC (lanes<32, scalar exec-mask branch)
        if (lane < 32) hb[(t & (CHUNK - 1)) * HROW + lane] = hnew;

        // broadcast new h to SGPRs
        #pragma unroll
        for (int k = 0; k < HH; ++k)
            hs[k] = __uint_as_float(
                __builtin_amdgcn_readlane(__float_as_uint(hnew), k));

        // ---- chunk flush: FC for 64 timesteps, coalesced ----
        if ((t & (CHUNK - 1)) == (CHUNK - 1)) {
            float acc = bfc;
            const float* row = hb + lane * HROW;
            #pragma unroll
            for (int u = 0; u < HH; ++u)
                acc = fmaf(row[u], W_fc[u], acc);   // W_fc[u] -> s_load
            out_b[(t - (CHUNK - 1)) + lane] = acc;
        }
    }
}

extern "C" void kernel_launch(void* const* d_in, const int* in_sizes, int n_in,
                              void* d_out, int out_size, void* d_ws, size_t ws_size,
                              hipStream_t stream) {
    const float* x    = (const float*)d_in[0];
    const float* W_ih = (const float*)d_in[1];
    const float* W_hh = (const float*)d_in[2];
    const float* b_ih = (const float*)d_in[3];
    const float* b_hh = (const float*)d_in[4];
    const float* W_fc = (const float*)d_in[5];
    const float* b_fc = (const float*)d_in[6];
    float* out = (float*)d_out;

    dim3 grid(BB / 4);
    dim3 block(256);
    lstm_fused_kernel<<<grid, block, 0, stream>>>(x, W_ih, W_hh, b_ih, b_hh,
                                                  W_fc, b_fc, out);
}

// Round 3
// 244.065 us; speedup vs baseline: 1.5745x; 1.2040x over previous
//
#include <hip/hip_runtime.h>

// LSTM: B=2048, T=512, INPUT=2, H=32, OUT=1. One wave per batch element.
// Lane j (0..63) owns gate rows j and j+64 of the 4H=128 gates:
//   lanes 0..31  -> i_j (row j),    g_j (row j+64)
//   lanes 32..63 -> f_{j-32} (row), o_{j-32} (row)
// Round 3: h broadcast via LDS (ds_read_b128 quads, same-address broadcast)
// instead of 32 v_readlane; recurrent dot as v_pk_fma_f32 (packed fp32) on
// {h[2k],h[2k+1]} pairs. FC head stays deferred in 64-step chunks.

#define BB 2048
#define TT 512
#define HH 32
#define CHUNK 64
#define HROW 33   // FC-history row stride: (lane+u)%32 -> 2-way alias = free

typedef float v2f __attribute__((ext_vector_type(2)));
typedef float v4f __attribute__((ext_vector_type(4)));

__device__ __forceinline__ float sigm(float x) {
    return __builtin_amdgcn_rcpf(1.0f + __expf(-x));
}

__global__ __launch_bounds__(256, 2) void lstm_fused_kernel(
    const float* __restrict__ x,     // [B, T, 2]
    const float* __restrict__ W_ih,  // [128, 2]
    const float* __restrict__ W_hh,  // [128, 32]
    const float* __restrict__ b_ih,  // [128]
    const float* __restrict__ b_hh,  // [128]
    const float* __restrict__ W_fc,  // [1, 32]
    const float* __restrict__ b_fc,  // [1]
    float* __restrict__ out)         // [B, T, 1]
{
    __shared__ float lds_x[4 * TT * 2];              // 16 KB  x staging
    __shared__ float lds_h[4 * CHUNK * HROW];        // 33 KB  FC history
    __shared__ __align__(16) float lds_bc[4][64];    // 1 KB   h broadcast

    const int lane = threadIdx.x & 63;
    const int wv   = threadIdx.x >> 6;
    const int b    = blockIdx.x * 4 + wv;

    // ---- stage x[T,2] (4 KB/elem) into LDS, coalesced float4 ----
    {
        const float4* xg = (const float4*)(x + (size_t)b * TT * 2);
        float4* xs = (float4*)(lds_x + wv * TT * 2);
        #pragma unroll
        for (int r = 0; r < 4; ++r) xs[r * 64 + lane] = xg[r * 64 + lane];
    }

    // ---- per-lane weights, packed in k-pairs for v_pk_fma_f32 ----
    const int rlo = lane;
    const int rhi = lane + 64;
    const float wihl0 = W_ih[rlo * 2 + 0], wihl1 = W_ih[rlo * 2 + 1];
    const float wihh0 = W_ih[rhi * 2 + 0], wihh1 = W_ih[rhi * 2 + 1];
    const float bl = b_ih[rlo] + b_hh[rlo];
    const float bh = b_ih[rhi] + b_hh[rhi];

    v2f wloq[HH / 2], whiq[HH / 2];
    #pragma unroll
    for (int k = 0; k < HH / 2; ++k) {
        wloq[k] = ((const v2f*)(W_hh + rlo * HH))[k];
        whiq[k] = ((const v2f*)(W_hh + rhi * HH))[k];
    }
    const float bfc = b_fc[0];

    // activation selectors (branch-free): lanes<32 hi-gate = tanh
    const float Mm = (lane < 32) ? 2.0f : 1.0f;
    const float Aa = (lane < 32) ? 2.0f : 1.0f;
    const float Bb = (lane < 32) ? -1.0f : 0.0f;

    float c = 0.0f;

    float* out_b = out + (size_t)b * TT;
    const float2* xw = (const float2*)(lds_x + wv * TT * 2);
    float* hb  = lds_h + wv * CHUNK * HROW;
    float* bcw = lds_bc[wv];
    const v4f* bcr = (const v4f*)bcw;

    bcw[lane] = 0.0f;   // h_{-1} = 0
    __syncthreads();

    #pragma unroll 1
    for (int t = 0; t < TT; ++t) {
        // broadcast h_{t-1}: 8 quad reads, all lanes same address
        v4f hq[8];
        #pragma unroll
        for (int q = 0; q < 8; ++q) hq[q] = bcr[q];

        float2 xt = xw[t];

        v2f aL, aH;
        aL.x = fmaf(xt.x, wihl0, fmaf(xt.y, wihl1, bl)); aL.y = 0.0f;
        aH.x = fmaf(xt.x, wihh0, fmaf(xt.y, wihh1, bh)); aH.y = 0.0f;

        // recurrent dot: 16+16 packed FMAs (v_pk_fma_f32)
        #pragma unroll
        for (int k = 0; k < HH / 2; ++k) {
            v2f hp = (k & 1)
                ? __builtin_shufflevector(hq[k >> 1], hq[k >> 1], 2, 3)
                : __builtin_shufflevector(hq[k >> 1], hq[k >> 1], 0, 1);
            aL = __builtin_elementwise_fma(hp, wloq[k], aL);
            aH = __builtin_elementwise_fma(hp, whiq[k], aH);
        }
        float glo = aL.x + aL.y;
        float ghi = aH.x + aH.y;

        float alo = sigm(glo);                      // i (lanes<32) / f
        float ahi = fmaf(Aa, sigm(Mm * ghi), Bb);   // tanh g / sigmoid o

        float fsw = __shfl_xor(alo, 32);            // lanes<32: f_j
        float osw = __shfl_xor(ahi, 32);            // lanes<32: o_j

        c = fmaf(fsw, c, alo * ahi);                // c = f*c + i*g (lanes<32)
        float tc = fmaf(2.0f, sigm(2.0f * c), -1.0f);
        float hnew = osw * tc;                      // h_j valid on lanes<32

        // publish h_t: all 64 lanes write (upper 32 garbage, never read)
        bcw[lane] = hnew;
        // FC history (predicated: only valid lanes)
        if (lane < 32) hb[(t & (CHUNK - 1)) * HROW + lane] = hnew;

        // ---- chunk flush: FC for 64 timesteps, coalesced store ----
        if ((t & (CHUNK - 1)) == (CHUNK - 1)) {
            float acc = bfc;
            const float* row = hb + lane * HROW;
            #pragma unroll
            for (int u = 0; u < HH; ++u)
                acc = fmaf(row[u], W_fc[u], acc);   // W_fc uniform -> s_load
            out_b[(t - (CHUNK - 1)) + lane] = acc;
        }
    }
}

extern "C" void kernel_launch(void* const* d_in, const int* in_sizes, int n_in,
                              void* d_out, int out_size, void* d_ws, size_t ws_size,
                              hipStream_t stream) {
    const float* x    = (const float*)d_in[0];
    const float* W_ih = (const float*)d_in[1];
    const float* W_hh = (const float*)d_in[2];
    const float* b_ih = (const float*)d_in[3];
    const float* b_hh = (const float*)d_in[4];
    const float* W_fc = (const float*)d_in[5];
    const float* b_fc = (const float*)d_in[6];
    float* out = (float*)d_out;

    dim3 grid(BB / 4);
    dim3 block(256);
    lstm_fused_kernel<<<grid, block, 0, stream>>>(x, W_ih, W_hh, b_ih, b_hh,
                                                  W_fc, b_fc, out);
}

// Round 4
// 233.103 us; speedup vs baseline: 1.6485x; 1.0470x over previous
//
#include <hip/hip_runtime.h>

// LSTM: B=2048, T=512, INPUT=2, H=32, OUT=1. One wave per batch element.
// Lane j (0..63) owns gate rows j and j+64:
//   lanes 0..31  -> i_j, g_j ; lanes 32..63 -> f_{j-32}, o_{j-32}
// h broadcast via LDS (same-address b128 reads); recurrent dot = v_pk_fma_f32,
// 4 chains of depth 8. Round 4: symmetric c/h on all lanes (no exec-mask
// divergence), single combined ds_write (broadcast | FC history), packed
// x-projection, chunked loop with unroll 2.

#define BB 2048
#define TT 512
#define HH 32
#define CHUNK 64
#define HROW 33   // FC-history row stride: (lane+u)%32 -> 2-way alias = free

typedef float v2f __attribute__((ext_vector_type(2)));
typedef float v4f __attribute__((ext_vector_type(4)));

__device__ __forceinline__ float sigm(float x) {
    return __builtin_amdgcn_rcpf(1.0f + __expf(-x));
}

__global__ __launch_bounds__(256, 2) void lstm_fused_kernel(
    const float* __restrict__ x,     // [B, T, 2]
    const float* __restrict__ W_ih,  // [128, 2]
    const float* __restrict__ W_hh,  // [128, 32]
    const float* __restrict__ b_ih,  // [128]
    const float* __restrict__ b_hh,  // [128]
    const float* __restrict__ W_fc,  // [1, 32]
    const float* __restrict__ b_fc,  // [1]
    float* __restrict__ out)         // [B, T, 1]
{
    __shared__ float lds_x[4 * TT * 2];              // 16 KB  x staging
    __shared__ float lds_h[4 * CHUNK * HROW];        // 33 KB  FC history
    __shared__ __align__(16) float lds_bc[4][64];    // 1 KB   h broadcast

    const int lane = threadIdx.x & 63;
    const int wv   = threadIdx.x >> 6;
    const int b    = blockIdx.x * 4 + wv;
    const bool low = (lane < 32);

    // ---- stage x[T,2] into LDS, coalesced float4 ----
    {
        const float4* xg = (const float4*)(x + (size_t)b * TT * 2);
        float4* xs = (float4*)(lds_x + wv * TT * 2);
        #pragma unroll
        for (int r = 0; r < 4; ++r) xs[r * 64 + lane] = xg[r * 64 + lane];
    }

    // ---- per-lane weights, packed in k-pairs for v_pk_fma_f32 ----
    const int rlo = lane;
    const int rhi = lane + 64;
    const v2f wihl = ((const v2f*)W_ih)[rlo];
    const v2f wihh = ((const v2f*)W_ih)[rhi];
    const float bl = b_ih[rlo] + b_hh[rlo];
    const float bh = b_ih[rhi] + b_hh[rhi];

    v2f wloq[HH / 2], whiq[HH / 2];
    #pragma unroll
    for (int k = 0; k < HH / 2; ++k) {
        wloq[k] = ((const v2f*)(W_hh + rlo * HH))[k];
        whiq[k] = ((const v2f*)(W_hh + rhi * HH))[k];
    }

    // FC weights (wave-uniform -> expect SGPRs)
    float wfc[HH];
    #pragma unroll
    for (int u = 0; u < HH; ++u) wfc[u] = W_fc[u];
    const float bfc = b_fc[0];

    // activation selectors: lanes<32 hi-gate = tanh (=2*sigm(2x)-1)
    const float Mm = low ? 2.0f : 1.0f;
    const float Aa = low ? 2.0f : 1.0f;
    const float Bb = low ? -1.0f : 0.0f;

    float c = 0.0f;

    float* out_b = out + (size_t)b * TT;
    const v2f* xw = (const v2f*)(lds_x + wv * TT * 2);
    float* hb  = lds_h + wv * CHUNK * HROW;
    float* bcw = lds_bc[wv];
    const v4f* bcr = (const v4f*)bcw;

    bcw[lane] = 0.0f;   // h_{-1} = 0
    __syncthreads();

    const v2f binitL = {bl, 0.0f};
    const v2f binitH = {bh, 0.0f};

    #pragma unroll 1
    for (int ch = 0; ch < TT / CHUNK; ++ch) {
        #pragma unroll 2
        for (int u = 0; u < CHUNK; ++u) {
            // broadcast h_{t-1}: 8 quad reads, all lanes same address
            v4f hq[8];
            #pragma unroll
            for (int q = 0; q < 8; ++q) hq[q] = bcr[q];

            v2f xt = xw[ch * CHUNK + u];

            // x-projection + bias, packed (horizontal add folds it in)
            v2f aL0 = __builtin_elementwise_fma(xt, wihl, binitL);
            v2f aH0 = __builtin_elementwise_fma(xt, wihh, binitH);
            v2f aL1 = {0.0f, 0.0f};
            v2f aH1 = {0.0f, 0.0f};

            // recurrent dot: 4 chains of 8 pk-FMAs
            #pragma unroll
            for (int k = 0; k < HH / 2; ++k) {
                v2f hp = (k & 1)
                    ? __builtin_shufflevector(hq[k >> 1], hq[k >> 1], 2, 3)
                    : __builtin_shufflevector(hq[k >> 1], hq[k >> 1], 0, 1);
                if (k < HH / 4) {
                    aL0 = __builtin_elementwise_fma(hp, wloq[k], aL0);
                    aH0 = __builtin_elementwise_fma(hp, whiq[k], aH0);
                } else {
                    aL1 = __builtin_elementwise_fma(hp, wloq[k], aL1);
                    aH1 = __builtin_elementwise_fma(hp, whiq[k], aH1);
                }
            }
            v2f aL = aL0 + aL1;
            v2f aH = aH0 + aH1;
            float glo = aL.x + aL.y;
            float ghi = aH.x + aH.y;

            float alo = sigm(glo);                      // i (low) / f (high)
            float ahi = fmaf(Aa, sigm(Mm * ghi), Bb);   // tanh g / sigmoid o

            float fsw = __shfl_xor(alo, 32);            // low: f ; high: i
            float osw = __shfl_xor(ahi, 32);            // low: o ; high: tanh g

            float iv = low ? alo : fsw;
            float fv = low ? fsw : alo;
            float gv = low ? ahi : osw;
            float ov = low ? osw : ahi;

            c = fmaf(fv, c, iv * gv);
            float tc = fmaf(2.0f, sigm(2.0f * c), -1.0f);
            float hnew = ov * tc;                       // valid on ALL lanes

            // single combined write: low lanes -> broadcast buffer,
            // high lanes -> FC history row u
            float* wr = low ? (bcw + lane) : (hb + u * HROW + (lane - 32));
            *wr = hnew;
        }

        // ---- chunk flush: FC for 64 timesteps, coalesced store ----
        float acc = bfc;
        const float* row = hb + lane * HROW;
        #pragma unroll
        for (int u = 0; u < HH; ++u)
            acc = fmaf(row[u], wfc[u], acc);
        out_b[ch * CHUNK + lane] = acc;
    }
}

extern "C" void kernel_launch(void* const* d_in, const int* in_sizes, int n_in,
                              void* d_out, int out_size, void* d_ws, size_t ws_size,
                              hipStream_t stream) {
    const float* x    = (const float*)d_in[0];
    const float* W_ih = (const float*)d_in[1];
    const float* W_hh = (const float*)d_in[2];
    const float* b_ih = (const float*)d_in[3];
    const float* b_hh = (const float*)d_in[4];
    const float* W_fc = (const float*)d_in[5];
    const float* b_fc = (const float*)d_in[6];
    float* out = (float*)d_out;

    dim3 grid(BB / 4);
    dim3 block(256);
    lstm_fused_kernel<<<grid, block, 0, stream>>>(x, W_ih, W_hh, b_ih, b_hh,
                                                  W_fc, b_fc, out);
}